// Round 13
// baseline (196.442 us; speedup 1.0000x reference)
//
#include <hip/hip_runtime.h>
#include <math.h>

constexpr int SEQ  = 2048;
constexpr int HID  = 1024;
constexpr int MTOT = 4096;     // B*S
constexpr int BH   = 32;       // B*nh

typedef _Float16 f16;
typedef _Float16 f16x4 __attribute__((ext_vector_type(4)));
typedef _Float16 f16x8 __attribute__((ext_vector_type(8)));
typedef float    f32x4 __attribute__((ext_vector_type(4)));

// async global->LDS, 16B per lane
__device__ __forceinline__ void gld16(const f16* g, f16* l) {
    __builtin_amdgcn_global_load_lds(
        (__attribute__((address_space(1))) void*)g,
        (__attribute__((address_space(3))) void*)l, 16, 0, 0);
}

// ---------------------------------------------------------------------------
// prep: z=0: Wq-Wk -> WqkT, z=1: Wv -> WvT, z=2: Wo -> WoT  (transpose+f16)
//       z=3: x fp32 -> f16 flat copy
// ---------------------------------------------------------------------------
__global__ __launch_bounds__(256) void prep(const float* __restrict__ x,
                                            const float* __restrict__ Wq,
                                            const float* __restrict__ Wk,
                                            const float* __restrict__ Wv,
                                            const float* __restrict__ Wo,
                                            f16* __restrict__ xh,
                                            f16* __restrict__ WqkT,
                                            f16* __restrict__ WvT,
                                            f16* __restrict__ WoT) {
    __shared__ f16 T[64][72];
    const int z = blockIdx.z;
    const int t = threadIdx.x;

    if (z == 3) {
        const int chunk = blockIdx.y * 16 + blockIdx.x;
        const float* src = x + (size_t)chunk * 16384;
        f16* dst = xh + (size_t)chunk * 16384;
#pragma unroll
        for (int it = 0; it < 16; it++) {
            const int i = it * 1024 + t * 4;
            float4 v = *(const float4*)(src + i);
            f16 o[4] = {(f16)v.x, (f16)v.y, (f16)v.z, (f16)v.w};
            *(ushort4*)(dst + i) = *(ushort4*)o;
        }
        return;
    }

    const float* W  = (z == 0) ? Wq : (z == 1) ? Wv : Wo;
    f16* WT = (z == 0) ? WqkT : (z == 1) ? WvT : WoT;
    const int k0 = blockIdx.x * 64, n0 = blockIdx.y * 64;
    const int r  = t >> 4;
    const int c4 = (t & 15) * 4;
#pragma unroll
    for (int rr = 0; rr < 64; rr += 16) {
        float4 w = *(const float4*)(W + (size_t)(k0 + rr + r) * HID + n0 + c4);
        if (z == 0) {
            float4 w2 = *(const float4*)(Wk + (size_t)(k0 + rr + r) * HID + n0 + c4);
            w.x -= w2.x; w.y -= w2.y; w.z -= w2.z; w.w -= w2.w;
        }
        T[c4 + 0][rr + r] = (f16)w.x;
        T[c4 + 1][rr + r] = (f16)w.y;
        T[c4 + 2][rr + r] = (f16)w.z;
        T[c4 + 3][rr + r] = (f16)w.w;
    }
    __syncthreads();
#pragma unroll
    for (int pp = 0; pp < 2; pp++) {
        const int nr = pp * 32 + (t >> 3);
        const int kc = (t & 7) * 8;
        *(uint4*)(WT + (size_t)(n0 + nr) * HID + k0 + kc) = *(uint4*)(&T[nr][kc]);
    }
}

// ---------------------------------------------------------------------------
// Fused projection GEMM (dif + vT): 128x64 tile, global_load_lds staging with
// XOR-octet swizzle. Epilogues via LDS bounce for coalesced stores.
// ---------------------------------------------------------------------------
__global__ __launch_bounds__(256, 4) void proj_gemm(const f16* __restrict__ A,
                                                    const f16* __restrict__ WqkT,
                                                    const f16* __restrict__ WvT,
                                                    const float* __restrict__ bq,
                                                    const float* __restrict__ bk,
                                                    const float* __restrict__ bv,
                                                    f16* __restrict__ dif,
                                                    f16* __restrict__ vT) {
    __shared__ f16 As[128 * 72];
    __shared__ f16 Bs[64 * 64];
    const int t = threadIdx.x;
    const int m0  = blockIdx.x * 128;
    const int n0g = blockIdx.y * 64;
    const bool isv = (n0g >= HID);
    const f16* BT = isv ? WvT : WqkT;
    const int n0 = n0g & (HID - 1);
    const int w = t >> 6, l = t & 63, quad = l >> 4, ln = l & 15;
    const int wm = w * 32;
    const int xk = ln & 7;

    const int srow8 = l >> 3;
    const int soct  = (l & 7) ^ srow8;
    const f16* pa = A  + (size_t)(m0 + w * 32 + srow8) * HID + soct * 8;
    const f16* pb = BT + (size_t)(n0 + w * 16 + srow8) * HID + soct * 8;

    f32x4 acc[2][4] = {};

    for (int k0 = 0; k0 < HID; k0 += 64) {
        __syncthreads();
#pragma unroll
        for (int c = 0; c < 4; c++)
            gld16(pa + (size_t)c * 8 * HID + k0, As + (w * 4 + c) * 512);
#pragma unroll
        for (int c = 0; c < 2; c++)
            gld16(pb + (size_t)c * 8 * HID + k0, Bs + (w * 2 + c) * 512);
        __syncthreads();

#pragma unroll
        for (int kh = 0; kh < 2; kh++) {
            f16x8 af[2], bf[4];
#pragma unroll
            for (int mt = 0; mt < 2; mt++) {
                const int row = wm + mt * 16 + ln;
                const int oct = (kh * 4 + quad) ^ xk;
                af[mt] = *(const f16x8*)(As + row * 64 + oct * 8);
            }
#pragma unroll
            for (int nt = 0; nt < 4; nt++) {
                const int row = nt * 16 + ln;
                const int oct = (kh * 4 + quad) ^ xk;
                bf[nt] = *(const f16x8*)(Bs + row * 64 + oct * 8);
            }
#pragma unroll
            for (int mt = 0; mt < 2; mt++)
#pragma unroll
                for (int nt = 0; nt < 4; nt++)
                    acc[mt][nt] = __builtin_amdgcn_mfma_f32_16x16x32_f16(
                        af[mt], bf[nt], acc[mt][nt], 0, 0, 0);
        }
    }

    __syncthreads();
    const int b_  = m0 >> 11;
    const int s0g = m0 & 2047;
    const int h_  = n0 >> 6;

    if (!isv) {
        float bb[4];
#pragma unroll
        for (int nt = 0; nt < 4; nt++) {
            const int nl = n0 + nt * 16 + ln;
            bb[nt] = bq[nl] - bk[nl];
        }
#pragma unroll
        for (int mt = 0; mt < 2; mt++)
#pragma unroll
            for (int nt = 0; nt < 4; nt++)
#pragma unroll
                for (int r = 0; r < 4; r++) {
                    const int sl = wm + mt * 16 + quad * 4 + r;
                    As[sl * 72 + nt * 16 + ln] = (f16)(acc[mt][nt][r] + bb[nt]);
                }
        __syncthreads();
        f16* base = dif + ((size_t)(b_ * 16 + h_) * SEQ + s0g) * 64;
        const int sl = t >> 1, eo = (t & 1) * 32;
#pragma unroll
        for (int i = 0; i < 4; i++)
            *(uint4*)(base + (size_t)sl * 64 + eo + i * 8) =
                *(uint4*)(&As[sl * 72 + eo + i * 8]);
    } else {
        float bb[4];
#pragma unroll
        for (int nt = 0; nt < 4; nt++)
            bb[nt] = bv[n0 + nt * 16 + ln];
#pragma unroll
        for (int mt = 0; mt < 2; mt++)
#pragma unroll
            for (int nt = 0; nt < 4; nt++)
#pragma unroll
                for (int r = 0; r < 4; r++) {
                    const int sl = wm + mt * 16 + quad * 4 + r;
                    As[(nt * 16 + ln) * 136 + sl] = (f16)(acc[mt][nt][r] + bb[nt]);
                }
        __syncthreads();
        const int eb = t >> 2, so = (t & 3) * 32;
        f16* base = vT + ((size_t)(b_ * 16 + h_) * 64 + eb) * SEQ + s0g + so;
#pragma unroll
        for (int i = 0; i < 4; i++)
            *(uint4*)(base + i * 8) = *(uint4*)(&As[eb * 136 + so + i * 8]);
    }
}

// ---------------------------------------------------------------------------
// Output GEMM: out = (C0+C1) @ WoT^T * 65536 + bo. 128x64 tile, dbuf LDS.
// ---------------------------------------------------------------------------
__global__ __launch_bounds__(256) void out_gemm(const f16* __restrict__ C0,
                                                const f16* __restrict__ C1,
                                                const f16* __restrict__ WoT,
                                                const float* __restrict__ bo,
                                                float* __restrict__ out) {
    __shared__ f16 As[2][128 * 72];
    __shared__ f16 Bs[2][64 * 72];
    const int t = threadIdx.x;
    const int m0 = blockIdx.x * 128, n0 = blockIdx.y * 64;
    const int w = t >> 6, l = t & 63, quad = l >> 4, ln = l & 15;
    const int wm = (w >> 1) * 64, wn = (w & 1) * 32;
    const int arow = t >> 1, ahalf = (t & 1) * 32;
    const int brow = t >> 2, boff = (t & 3) * 16;

    const f16* pa0 = C0  + (size_t)(m0 + arow) * HID + ahalf;
    const f16* pa1 = C1  + (size_t)(m0 + arow) * HID + ahalf;
    const f16* pb  = WoT + (size_t)(n0 + brow) * HID + boff;

    f16x8 a0 = *(const f16x8*)(pa0)      + *(const f16x8*)(pa1);
    f16x8 a1 = *(const f16x8*)(pa0 + 8)  + *(const f16x8*)(pa1 + 8);
    f16x8 a2 = *(const f16x8*)(pa0 + 16) + *(const f16x8*)(pa1 + 16);
    f16x8 a3 = *(const f16x8*)(pa0 + 24) + *(const f16x8*)(pa1 + 24);
    uint4 b0 = *(const uint4*)(pb), b1 = *(const uint4*)(pb + 8);

    f32x4 acc[4][2] = {};
    int buf = 0;

    for (int k0 = 0; k0 < HID; k0 += 64) {
        f16* da = As[buf] + arow * 72 + ahalf;
        *(f16x8*)(da)      = a0; *(f16x8*)(da + 8)  = a1;
        *(f16x8*)(da + 16) = a2; *(f16x8*)(da + 24) = a3;
        f16* db = Bs[buf] + brow * 72 + boff;
        *(uint4*)(db) = b0; *(uint4*)(db + 8) = b1;
        __syncthreads();
        if (k0 + 64 < HID) {
            const int kn = k0 + 64;
            a0 = *(const f16x8*)(pa0 + kn)      + *(const f16x8*)(pa1 + kn);
            a1 = *(const f16x8*)(pa0 + kn + 8)  + *(const f16x8*)(pa1 + kn + 8);
            a2 = *(const f16x8*)(pa0 + kn + 16) + *(const f16x8*)(pa1 + kn + 16);
            a3 = *(const f16x8*)(pa0 + kn + 24) + *(const f16x8*)(pa1 + kn + 24);
            b0 = *(const uint4*)(pb + kn); b1 = *(const uint4*)(pb + kn + 8);
        }
#pragma unroll
        for (int kh = 0; kh < 2; kh++) {
            f16x8 af[4], bf[2];
#pragma unroll
            for (int mt = 0; mt < 4; mt++)
                af[mt] = *(const f16x8*)(As[buf] + (wm + mt * 16 + ln) * 72 + kh * 32 + quad * 8);
#pragma unroll
            for (int nt = 0; nt < 2; nt++)
                bf[nt] = *(const f16x8*)(Bs[buf] + (wn + nt * 16 + ln) * 72 + kh * 32 + quad * 8);
#pragma unroll
            for (int mt = 0; mt < 4; mt++)
#pragma unroll
                for (int nt = 0; nt < 2; nt++)
                    acc[mt][nt] = __builtin_amdgcn_mfma_f32_16x16x32_f16(
                        af[mt], bf[nt], acc[mt][nt], 0, 0, 0);
        }
        buf ^= 1;
    }

#pragma unroll
    for (int mt = 0; mt < 4; mt++)
#pragma unroll
        for (int nt = 0; nt < 2; nt++) {
            const int n = n0 + wn + nt * 16 + ln;
            const float bb = bo[n];
            const int m_base = m0 + wm + mt * 16 + quad * 4;
#pragma unroll
            for (int r = 0; r < 4; r++)
                out[(size_t)(m_base + r) * HID + n] =
                    acc[mt][nt][r] * 65536.0f + bb;
        }
}

// ---------------------------------------------------------------------------
// fp16 MFMA attention R13: single-barrier K-loop with double-buffered
// global_load_lds staging (loads in flight across the whole compute phase).
// XOR-octet swizzled pitch-64 LDS (gld16-contiguous, bank-clean frag reads).
// S^T=K.Q^T, P in registers -> 16x16x16 PV. XCD-local 1D grid, 4 blk/CU.
// LDS: Qs 8 KB + 2 x (K 8 + V 8) = 40 KB.
// ---------------------------------------------------------------------------
__global__ __launch_bounds__(256, 4) void attn_f16(const f16* __restrict__ dif,
                                                   const f16* __restrict__ vT,
                                                   f16* __restrict__ ctx0,
                                                   f16* __restrict__ ctx1) {
    __shared__ f16 Qs[64 * 64];
    __shared__ f16 KV[2][2 * 64 * 64];   // [buf][ K(64x64) | V(64x64) ]

    // XCD-local decode: bh = (blk&7)*4 + ((blk>>3)&3)
    const int blk = blockIdx.x;
    const int g   = blk >> 3;
    const int bh  = (blk & 7) * 4 + (g & 3);
    const int pq  = (g >> 2) & 15;
    const int ks  = g >> 6;

    f16* Cout = ks ? ctx1 : ctx0;
    const f16* D  = dif + (size_t)bh * SEQ * 64;
    const f16* VT = vT  + (size_t)bh * 64 * SEQ;
    const int b = bh >> 4, h = bh & 15;
    const int t = threadIdx.x, w = t >> 6, l = t & 63, quad = l >> 4, ln = l & 15;
    const int qh = w >> 1, jh = w & 1;
    const int xk = ln & 7;

    // staging decode: lane l -> row (l>>3) within 8-row chunk, xor'd octet
    const int srow = l >> 3;
    const int soct = (l & 7) ^ srow;

    for (int half = 0; half < 2; half++) {
        const int qt = half ? (31 - pq) : pq;
        const int i0 = qt * 64;
        __syncthreads();   // prior half's LDS use complete

        // ---- stage Q (gld16, xor layout) + first K/V tile into buf0 ----
#pragma unroll
        for (int c = 0; c < 2; c++)
            gld16(D + (size_t)(i0 + w * 16 + c * 8 + srow) * 64 + soct * 8,
                  Qs + (w * 16 + c * 8) * 64);
        const int kt0 = qt + ks;
        const int nit = (kt0 < 32) ? (32 - kt0 + 1) / 2 : 0;
        if (nit > 0) {
            const int j0 = kt0 * 64;
#pragma unroll
            for (int c = 0; c < 2; c++) {
                gld16(D + (size_t)(j0 + w * 16 + c * 8 + srow) * 64 + soct * 8,
                      KV[0] + (w * 16 + c * 8) * 64);
                gld16(VT + (size_t)(w * 16 + c * 8 + srow) * SEQ + j0 + soct * 8,
                      KV[0] + 4096 + (w * 16 + c * 8) * 64);
            }
        }
        __syncthreads();   // Q + KV0 ready (vmcnt drained)

        // Q frags to regs (loop-invariant)
        f16x8 aq[2][2];   // [mt][kh]
#pragma unroll
        for (int mt = 0; mt < 2; mt++)
#pragma unroll
            for (int kh = 0; kh < 2; kh++)
                aq[mt][kh] = *(const f16x8*)(Qs + (qh * 32 + mt * 16 + ln) * 64
                                             + ((kh * 4 + quad) ^ xk) * 8);

        f32x4 acc[2][4] = {};   // [mt(q)][nte(e)]

        for (int it = 0; it < nit; it++) {
            const int kt = kt0 + it * 2;
            const int j0 = kt * 64;
            const f16* Ks = KV[it & 1];
            const f16* Vs = KV[it & 1] + 4096;

            // issue next tile's async loads into the other buffer
            if (it + 1 < nit) {
                const int j2 = j0 + 128;
                f16* Kn = KV[(it + 1) & 1];
#pragma unroll
                for (int c = 0; c < 2; c++) {
                    gld16(D + (size_t)(j2 + w * 16 + c * 8 + srow) * 64 + soct * 8,
                          Kn + (w * 16 + c * 8) * 64);
                    gld16(VT + (size_t)(w * 16 + c * 8 + srow) * SEQ + j2 + soct * 8,
                          Kn + 4096 + (w * 16 + c * 8) * 64);
                }
            }

            // ---- S^T = K . Q^T (32 j-rows x 32 q-cols per wave) ----
            f32x4 st[2][2] = {};   // [ntj][mt]
#pragma unroll
            for (int kh = 0; kh < 2; kh++)
#pragma unroll
                for (int nt = 0; nt < 2; nt++) {
                    const int row = jh * 32 + nt * 16 + ln;
                    f16x8 ak = *(const f16x8*)(Ks + row * 64
                                               + ((kh * 4 + quad) ^ xk) * 8);
#pragma unroll
                    for (int mt = 0; mt < 2; mt++)
                        st[nt][mt] = __builtin_amdgcn_mfma_f32_16x16x32_f16(
                            ak, aq[mt][kh], st[nt][mt], 0, 0, 0);
                }

            // ---- P in registers (S^T C-layout == 16x16x16 A-layout) ----
            const bool full = (kt > qt);
            f16x4 pf[2][2];   // [ntj][mt]
#pragma unroll
            for (int nt = 0; nt < 2; nt++)
#pragma unroll
                for (int mt = 0; mt < 2; mt++) {
                    const int gi = i0 + qh * 32 + mt * 16 + ln;
#pragma unroll
                    for (int r = 0; r < 4; r++) {
                        const int gj = j0 + jh * 32 + nt * 16 + quad * 4 + r;
                        float p = (full || (gj > gi))
                                      ? fminf(__expf(fmaf(st[nt][mt][r], -0.5f,
                                                          -11.090354888959125f)),
                                              60000.0f)
                                      : 0.0f;
                        pf[nt][mt][r] = (f16)p;
                    }
                }

            // ---- ctx += P @ V via 16x16x16 (V stored [e][j], xor octets) ----
#pragma unroll
            for (int nt = 0; nt < 2; nt++)
#pragma unroll
                for (int nte = 0; nte < 4; nte++) {
                    const int row = nte * 16 + ln;
                    const int octl = jh * 4 + nt * 2 + (quad >> 1);
                    f16x4 bv = *(const f16x4*)(Vs + row * 64
                                               + (octl ^ xk) * 8 + (quad & 1) * 4);
#pragma unroll
                    for (int mt = 0; mt < 2; mt++)
                        acc[mt][nte] = __builtin_amdgcn_mfma_f32_16x16x16f16(
                            pf[nt][mt], bv, acc[mt][nte], 0, 0, 0);
                }

            __syncthreads();   // next buf ready; current buf reads done
        }

        // ---- cross-jh reduction via Qs (xor-mapped scalar scratch) ----
        if (jh == 1) {
#pragma unroll
            for (int mt = 0; mt < 2; mt++)
#pragma unroll
                for (int nte = 0; nte < 4; nte++)
#pragma unroll
                    for (int r = 0; r < 4; r++) {
                        const int row = qh * 32 + mt * 16 + quad * 4 + r;
                        const int c   = nte * 16 + ln;
                        Qs[row * 64 + (((c >> 3) ^ (row & 7)) * 8) + (c & 7)] =
                            (f16)acc[mt][nte][r];
                    }
        }
        __syncthreads();
        if (jh == 0) {
#pragma unroll
            for (int mt = 0; mt < 2; mt++)
#pragma unroll
                for (int nte = 0; nte < 4; nte++)
#pragma unroll
                    for (int r = 0; r < 4; r++) {
                        const int row = qh * 32 + mt * 16 + quad * 4 + r;
                        const int c   = nte * 16 + ln;
                        float v = acc[mt][nte][r]
                                + (float)Qs[row * 64 + (((c >> 3) ^ (row & 7)) * 8) + (c & 7)];
                        Cout[(size_t)(b * SEQ + i0 + row) * HID + h * 64 + c] = (f16)v;
                    }
        }
    }
}

// ---------------------------------------------------------------------------
extern "C" void kernel_launch(void* const* d_in, const int* in_sizes, int n_in,
                              void* d_out, int out_size, void* d_ws, size_t ws_size,
                              hipStream_t stream) {
    const float* x  = (const float*)d_in[0];
    const float* Wq = (const float*)d_in[1];
    const float* bq = (const float*)d_in[2];
    const float* Wk = (const float*)d_in[3];
    const float* bk = (const float*)d_in[4];
    const float* Wv = (const float*)d_in[5];
    const float* bv = (const float*)d_in[6];
    const float* Wo = (const float*)d_in[7];
    const float* bo = (const float*)d_in[8];
    float* out = (float*)d_out;

    char* ws = (char*)d_ws;
    f16* xh   = (f16*)(ws);               // 8 MB  [M][1024]
    f16* WqkT = (f16*)(ws + (8 << 20));   // 2 MB  [n][k]
    f16* WvT  = (f16*)(ws + (10 << 20));  // 2 MB
    f16* WoT  = (f16*)(ws + (12 << 20));  // 2 MB
    f16* dif  = (f16*)(ws + (14 << 20));  // 8 MB  [bh][s][64]
    f16* vT   = (f16*)(ws + (22 << 20));  // 8 MB  [bh][e][s]
    f16* ctx0 = (f16*)(ws + (30 << 20));  // 8 MB  partial (x 2^-16)
    f16* ctx1 = (f16*)(ws + (38 << 20));  // 8 MB  partial

    prep<<<dim3(16, 16, 4), 256, 0, stream>>>(x, Wq, Wk, Wv, Wo,
                                              xh, WqkT, WvT, WoT);
    proj_gemm<<<dim3(MTOT / 128, 32), 256, 0, stream>>>(xh, WqkT, WvT,
                                                        bq, bk, bv, dif, vT);
    attn_f16<<<1024, 256, 0, stream>>>(dif, vT, ctx0, ctx1);
    out_gemm<<<dim3(MTOT / 128, 16), 256, 0, stream>>>(ctx0, ctx1, WoT, bo, out);
}

// Round 14
// 177.744 us; speedup vs baseline: 1.1052x; 1.1052x over previous
//
#include <hip/hip_runtime.h>
#include <math.h>

constexpr int SEQ  = 2048;
constexpr int HID  = 1024;
constexpr int MTOT = 4096;     // B*S
constexpr int BH   = 32;       // B*nh

typedef _Float16 f16;
typedef _Float16 f16x4 __attribute__((ext_vector_type(4)));
typedef _Float16 f16x8 __attribute__((ext_vector_type(8)));
typedef float    f32x4 __attribute__((ext_vector_type(4)));

// async global->LDS, 16B per lane
__device__ __forceinline__ void gld16(const f16* g, f16* l) {
    __builtin_amdgcn_global_load_lds(
        (__attribute__((address_space(1))) void*)g,
        (__attribute__((address_space(3))) void*)l, 16, 0, 0);
}

// ---------------------------------------------------------------------------
// prep: z=0: Wq-Wk -> WqkT, z=1: Wv -> WvT, z=2: Wo -> WoT  (transpose+f16)
//       z=3: x fp32 -> f16 flat copy
// ---------------------------------------------------------------------------
__global__ __launch_bounds__(256) void prep(const float* __restrict__ x,
                                            const float* __restrict__ Wq,
                                            const float* __restrict__ Wk,
                                            const float* __restrict__ Wv,
                                            const float* __restrict__ Wo,
                                            f16* __restrict__ xh,
                                            f16* __restrict__ WqkT,
                                            f16* __restrict__ WvT,
                                            f16* __restrict__ WoT) {
    __shared__ f16 T[64][72];
    const int z = blockIdx.z;
    const int t = threadIdx.x;

    if (z == 3) {
        const int chunk = blockIdx.y * 16 + blockIdx.x;
        const float* src = x + (size_t)chunk * 16384;
        f16* dst = xh + (size_t)chunk * 16384;
#pragma unroll
        for (int it = 0; it < 16; it++) {
            const int i = it * 1024 + t * 4;
            float4 v = *(const float4*)(src + i);
            f16 o[4] = {(f16)v.x, (f16)v.y, (f16)v.z, (f16)v.w};
            *(ushort4*)(dst + i) = *(ushort4*)o;
        }
        return;
    }

    const float* W  = (z == 0) ? Wq : (z == 1) ? Wv : Wo;
    f16* WT = (z == 0) ? WqkT : (z == 1) ? WvT : WoT;
    const int k0 = blockIdx.x * 64, n0 = blockIdx.y * 64;
    const int r  = t >> 4;
    const int c4 = (t & 15) * 4;
#pragma unroll
    for (int rr = 0; rr < 64; rr += 16) {
        float4 w = *(const float4*)(W + (size_t)(k0 + rr + r) * HID + n0 + c4);
        if (z == 0) {
            float4 w2 = *(const float4*)(Wk + (size_t)(k0 + rr + r) * HID + n0 + c4);
            w.x -= w2.x; w.y -= w2.y; w.z -= w2.z; w.w -= w2.w;
        }
        T[c4 + 0][rr + r] = (f16)w.x;
        T[c4 + 1][rr + r] = (f16)w.y;
        T[c4 + 2][rr + r] = (f16)w.z;
        T[c4 + 3][rr + r] = (f16)w.w;
    }
    __syncthreads();
#pragma unroll
    for (int pp = 0; pp < 2; pp++) {
        const int nr = pp * 32 + (t >> 3);
        const int kc = (t & 7) * 8;
        *(uint4*)(WT + (size_t)(n0 + nr) * HID + k0 + kc) = *(uint4*)(&T[nr][kc]);
    }
}

// ---------------------------------------------------------------------------
// Fused projection GEMM R14: 128x128 tile (m97-size), gld16 staging with
// XOR-octet swizzle, 2-barrier K-loop. Grid 32x16 = 512 blocks (2/CU).
// Epilogue: two 64-col passes via LDS bounce for coalesced 16B stores.
// ---------------------------------------------------------------------------
__global__ __launch_bounds__(256, 2) void proj_gemm(const f16* __restrict__ A,
                                                    const f16* __restrict__ WqkT,
                                                    const f16* __restrict__ WvT,
                                                    const float* __restrict__ bq,
                                                    const float* __restrict__ bk,
                                                    const float* __restrict__ bv,
                                                    f16* __restrict__ dif,
                                                    f16* __restrict__ vT) {
    __shared__ f16 S[2 * 128 * 64];      // As | Bs (32 KB); reused by epilogue
    f16* As = S;
    f16* Bs = S + 128 * 64;

    const int t = threadIdx.x;
    const int m0  = blockIdx.x * 128;
    const int n0g = blockIdx.y * 128;
    const bool isv = (n0g >= HID);
    const f16* BT = isv ? WvT : WqkT;
    const int n0 = n0g & (HID - 1);
    const int w = t >> 6, l = t & 63, quad = l >> 4, ln = l & 15;
    const int wm = (w >> 1) * 64, wn = (w & 1) * 64;
    const int xk = ln & 7;

    const int srow8 = l >> 3;
    const int soct  = (l & 7) ^ srow8;
    const f16* pa = A  + (size_t)(m0 + w * 32 + srow8) * HID + soct * 8;
    const f16* pb = BT + (size_t)(n0 + w * 32 + srow8) * HID + soct * 8;

    f32x4 acc[4][4] = {};

    for (int k0 = 0; k0 < HID; k0 += 64) {
        __syncthreads();                 // prev iter frag reads done
#pragma unroll
        for (int c = 0; c < 4; c++) {
            gld16(pa + (size_t)c * 8 * HID + k0, As + (w * 32 + c * 8) * 64);
            gld16(pb + (size_t)c * 8 * HID + k0, Bs + (w * 32 + c * 8) * 64);
        }
        __syncthreads();                 // drains vmcnt, data visible

#pragma unroll
        for (int kh = 0; kh < 2; kh++) {
            f16x8 af[4], bf[4];
            const int oct = (kh * 4 + quad) ^ xk;
#pragma unroll
            for (int mt = 0; mt < 4; mt++)
                af[mt] = *(const f16x8*)(As + (wm + mt * 16 + ln) * 64 + oct * 8);
#pragma unroll
            for (int nt = 0; nt < 4; nt++)
                bf[nt] = *(const f16x8*)(Bs + (wn + nt * 16 + ln) * 64 + oct * 8);
#pragma unroll
            for (int mt = 0; mt < 4; mt++)
#pragma unroll
                for (int nt = 0; nt < 4; nt++)
                    acc[mt][nt] = __builtin_amdgcn_mfma_f32_16x16x32_f16(
                        af[mt], bf[nt], acc[mt][nt], 0, 0, 0);
        }
    }

    // ---- epilogue: two 64-col passes via LDS bounce ----
    __syncthreads();
    const int b_  = m0 >> 11;
    const int s0g = m0 & 2047;

    for (int p = 0; p < 2; p++) {
        const int h_ = (n0 + p * 64) >> 6;
        if ((w & 1) == p) {              // waves owning this col-half
            if (!isv) {
                float bb[4];
#pragma unroll
                for (int nt = 0; nt < 4; nt++)
                    bb[nt] = bq[n0 + p * 64 + nt * 16 + ln]
                           - bk[n0 + p * 64 + nt * 16 + ln];
#pragma unroll
                for (int mt = 0; mt < 4; mt++)
#pragma unroll
                    for (int nt = 0; nt < 4; nt++)
#pragma unroll
                        for (int r = 0; r < 4; r++) {
                            const int sl = wm + mt * 16 + quad * 4 + r;
                            S[sl * 72 + nt * 16 + ln] =
                                (f16)(acc[mt][nt][r] + bb[nt]);
                        }
            } else {
                float bb[4];
#pragma unroll
                for (int nt = 0; nt < 4; nt++)
                    bb[nt] = bv[n0 + p * 64 + nt * 16 + ln];
#pragma unroll
                for (int mt = 0; mt < 4; mt++)
#pragma unroll
                    for (int nt = 0; nt < 4; nt++)
#pragma unroll
                        for (int r = 0; r < 4; r++) {
                            const int sl = wm + mt * 16 + quad * 4 + r;
                            S[(nt * 16 + ln) * 136 + sl] =
                                (f16)(acc[mt][nt][r] + bb[nt]);
                        }
            }
        }
        __syncthreads();
        if (!isv) {                      // dif: [bh][s][64], 128 rows
            f16* base = dif + ((size_t)(b_ * 16 + h_) * SEQ + s0g) * 64;
            const int sl = t >> 1, eo = (t & 1) * 32;
#pragma unroll
            for (int i = 0; i < 4; i++)
                *(uint4*)(base + (size_t)sl * 64 + eo + i * 8) =
                    *(uint4*)(&S[sl * 72 + eo + i * 8]);
        } else {                         // vT: [bh][e][s], 64 e-rows x 128 s
            const int eb = t >> 2, so = (t & 3) * 32;
            f16* base = vT + ((size_t)(b_ * 16 + h_) * 64 + eb) * SEQ + s0g + so;
#pragma unroll
            for (int i = 0; i < 4; i++)
                *(uint4*)(base + i * 8) = *(uint4*)(&S[eb * 136 + so + i * 8]);
        }
        __syncthreads();
    }
}

// ---------------------------------------------------------------------------
// Output GEMM: out = (C0+C1) @ WoT^T * 65536 + bo. 128x64 tile, dbuf LDS.
// ---------------------------------------------------------------------------
__global__ __launch_bounds__(256) void out_gemm(const f16* __restrict__ C0,
                                                const f16* __restrict__ C1,
                                                const f16* __restrict__ WoT,
                                                const float* __restrict__ bo,
                                                float* __restrict__ out) {
    __shared__ f16 As[2][128 * 72];
    __shared__ f16 Bs[2][64 * 72];
    const int t = threadIdx.x;
    const int m0 = blockIdx.x * 128, n0 = blockIdx.y * 64;
    const int w = t >> 6, l = t & 63, quad = l >> 4, ln = l & 15;
    const int wm = (w >> 1) * 64, wn = (w & 1) * 32;
    const int arow = t >> 1, ahalf = (t & 1) * 32;
    const int brow = t >> 2, boff = (t & 3) * 16;

    const f16* pa0 = C0  + (size_t)(m0 + arow) * HID + ahalf;
    const f16* pa1 = C1  + (size_t)(m0 + arow) * HID + ahalf;
    const f16* pb  = WoT + (size_t)(n0 + brow) * HID + boff;

    f16x8 a0 = *(const f16x8*)(pa0)      + *(const f16x8*)(pa1);
    f16x8 a1 = *(const f16x8*)(pa0 + 8)  + *(const f16x8*)(pa1 + 8);
    f16x8 a2 = *(const f16x8*)(pa0 + 16) + *(const f16x8*)(pa1 + 16);
    f16x8 a3 = *(const f16x8*)(pa0 + 24) + *(const f16x8*)(pa1 + 24);
    uint4 b0 = *(const uint4*)(pb), b1 = *(const uint4*)(pb + 8);

    f32x4 acc[4][2] = {};
    int buf = 0;

    for (int k0 = 0; k0 < HID; k0 += 64) {
        f16* da = As[buf] + arow * 72 + ahalf;
        *(f16x8*)(da)      = a0; *(f16x8*)(da + 8)  = a1;
        *(f16x8*)(da + 16) = a2; *(f16x8*)(da + 24) = a3;
        f16* db = Bs[buf] + brow * 72 + boff;
        *(uint4*)(db) = b0; *(uint4*)(db + 8) = b1;
        __syncthreads();
        if (k0 + 64 < HID) {
            const int kn = k0 + 64;
            a0 = *(const f16x8*)(pa0 + kn)      + *(const f16x8*)(pa1 + kn);
            a1 = *(const f16x8*)(pa0 + kn + 8)  + *(const f16x8*)(pa1 + kn + 8);
            a2 = *(const f16x8*)(pa0 + kn + 16) + *(const f16x8*)(pa1 + kn + 16);
            a3 = *(const f16x8*)(pa0 + kn + 24) + *(const f16x8*)(pa1 + kn + 24);
            b0 = *(const uint4*)(pb + kn); b1 = *(const uint4*)(pb + kn + 8);
        }
#pragma unroll
        for (int kh = 0; kh < 2; kh++) {
            f16x8 af[4], bf[2];
#pragma unroll
            for (int mt = 0; mt < 4; mt++)
                af[mt] = *(const f16x8*)(As[buf] + (wm + mt * 16 + ln) * 72 + kh * 32 + quad * 8);
#pragma unroll
            for (int nt = 0; nt < 2; nt++)
                bf[nt] = *(const f16x8*)(Bs[buf] + (wn + nt * 16 + ln) * 72 + kh * 32 + quad * 8);
#pragma unroll
            for (int mt = 0; mt < 4; mt++)
#pragma unroll
                for (int nt = 0; nt < 2; nt++)
                    acc[mt][nt] = __builtin_amdgcn_mfma_f32_16x16x32_f16(
                        af[mt], bf[nt], acc[mt][nt], 0, 0, 0);
        }
        buf ^= 1;
    }

#pragma unroll
    for (int mt = 0; mt < 4; mt++)
#pragma unroll
        for (int nt = 0; nt < 2; nt++) {
            const int n = n0 + wn + nt * 16 + ln;
            const float bb = bo[n];
            const int m_base = m0 + wm + mt * 16 + quad * 4;
#pragma unroll
            for (int r = 0; r < 4; r++)
                out[(size_t)(m_base + r) * HID + n] =
                    acc[mt][nt][r] * 65536.0f + bb;
        }
}

// ---------------------------------------------------------------------------
// fp16 MFMA attention (R12 known-good, 43.6 us): S^T = K.Q^T; P in registers
// (S^T C-layout == 16x16x16 A-layout) -> PV via v_mfma_f32_16x16x16f16.
// XCD-aware 1D grid. LDS 27.6 KB; 1024 blocks = 4/CU.
// ---------------------------------------------------------------------------
__global__ __launch_bounds__(256, 4) void attn_f16(const f16* __restrict__ dif,
                                                   const f16* __restrict__ vT,
                                                   f16* __restrict__ ctx0,
                                                   f16* __restrict__ ctx1) {
    __shared__ f16 Qs[64 * 72];
    __shared__ f16 Ks[64 * 72];
    __shared__ f16 Vs[64 * 72];

    const int blk = blockIdx.x;
    const int g   = blk >> 3;
    const int bh  = (blk & 7) * 4 + (g & 3);
    const int pq  = (g >> 2) & 15;
    const int ks  = g >> 6;

    f16* Cout = ks ? ctx1 : ctx0;
    const f16* D  = dif + (size_t)bh * SEQ * 64;
    const f16* VT = vT  + (size_t)bh * 64 * SEQ;
    const int b = bh >> 4, h = bh & 15;
    const int t = threadIdx.x, w = t >> 6, l = t & 63, quad = l >> 4, ln = l & 15;
    const int qh = w >> 1, jh = w & 1;
    const int ve = t >> 2, vc = (t & 3) * 16;

    for (int half = 0; half < 2; half++) {
        const int qt = half ? (31 - pq) : pq;
        const int i0 = qt * 64;
        __syncthreads();

#pragma unroll
        for (int rr = 0; rr < 2; rr++) {
            const int o = rr * 2048 + t * 8;
            uint4 v = *(const uint4*)(D + i0 * 64 + o);
            *(uint4*)(Qs + (o >> 6) * 72 + (o & 63)) = v;
        }
        __syncthreads();
        f16x8 aq[2][2];
#pragma unroll
        for (int mt = 0; mt < 2; mt++)
#pragma unroll
            for (int kh = 0; kh < 2; kh++)
                aq[mt][kh] = *(const f16x8*)(Qs + (qh * 32 + mt * 16 + ln) * 72
                                             + kh * 32 + quad * 8);

        f32x4 acc[2][4] = {};
        const int kt0 = qt + ks;

        uint4 kr0, kr1, vr0, vr1;
        if (kt0 < 32) {
            const int j0 = kt0 * 64;
            kr0 = *(const uint4*)(D + j0 * 64 + t * 8);
            kr1 = *(const uint4*)(D + j0 * 64 + 2048 + t * 8);
            vr0 = *(const uint4*)(VT + (size_t)ve * SEQ + j0 + vc);
            vr1 = *(const uint4*)(VT + (size_t)ve * SEQ + j0 + vc + 8);
        }

        for (int kt = kt0; kt < 32; kt += 2) {
            const int j0 = kt * 64;
            __syncthreads();

            {
                const int o0 = t * 8, o1 = 2048 + t * 8;
                *(uint4*)(Ks + (o0 >> 6) * 72 + (o0 & 63)) = kr0;
                *(uint4*)(Ks + (o1 >> 6) * 72 + (o1 & 63)) = kr1;
                *(uint4*)(Vs + ve * 72 + vc)     = vr0;
                *(uint4*)(Vs + ve * 72 + vc + 8) = vr1;
            }
            __syncthreads();

            if (kt + 2 < 32) {
                const int j2 = (kt + 2) * 64;
                kr0 = *(const uint4*)(D + j2 * 64 + t * 8);
                kr1 = *(const uint4*)(D + j2 * 64 + 2048 + t * 8);
                vr0 = *(const uint4*)(VT + (size_t)ve * SEQ + j2 + vc);
                vr1 = *(const uint4*)(VT + (size_t)ve * SEQ + j2 + vc + 8);
            }

            f32x4 st[2][2] = {};
#pragma unroll
            for (int kh = 0; kh < 2; kh++)
#pragma unroll
                for (int nt = 0; nt < 2; nt++) {
                    f16x8 ak = *(const f16x8*)(Ks + (jh * 32 + nt * 16 + ln) * 72
                                               + kh * 32 + quad * 8);
#pragma unroll
                    for (int mt = 0; mt < 2; mt++)
                        st[nt][mt] = __builtin_amdgcn_mfma_f32_16x16x32_f16(
                            ak, aq[mt][kh], st[nt][mt], 0, 0, 0);
                }

            const bool full = (kt > qt);
            f16x4 pf[2][2];
#pragma unroll
            for (int nt = 0; nt < 2; nt++)
#pragma unroll
                for (int mt = 0; mt < 2; mt++) {
                    const int gi = i0 + qh * 32 + mt * 16 + ln;
#pragma unroll
                    for (int r = 0; r < 4; r++) {
                        const int gj = j0 + jh * 32 + nt * 16 + quad * 4 + r;
                        float p = (full || (gj > gi))
                                      ? fminf(__expf(fmaf(st[nt][mt][r], -0.5f,
                                                          -11.090354888959125f)),
                                              60000.0f)
                                      : 0.0f;
                        pf[nt][mt][r] = (f16)p;
                    }
                }

#pragma unroll
            for (int nt = 0; nt < 2; nt++)
#pragma unroll
                for (int nte = 0; nte < 4; nte++) {
                    f16x4 bv = *(const f16x4*)(Vs + (nte * 16 + ln) * 72
                                               + jh * 32 + nt * 16 + quad * 4);
#pragma unroll
                    for (int mt = 0; mt < 2; mt++)
                        acc[mt][nte] = __builtin_amdgcn_mfma_f32_16x16x16f16(
                            pf[nt][mt], bv, acc[mt][nte], 0, 0, 0);
                }
        }

        __syncthreads();
        if (jh == 1) {
#pragma unroll
            for (int mt = 0; mt < 2; mt++)
#pragma unroll
                for (int nte = 0; nte < 4; nte++)
#pragma unroll
                    for (int r = 0; r < 4; r++)
                        Qs[(qh * 32 + mt * 16 + quad * 4 + r) * 72 + nte * 16 + ln] =
                            (f16)acc[mt][nte][r];
        }
        __syncthreads();
        if (jh == 0) {
#pragma unroll
            for (int mt = 0; mt < 2; mt++)
#pragma unroll
                for (int nte = 0; nte < 4; nte++)
#pragma unroll
                    for (int r = 0; r < 4; r++) {
                        const int iloc = qh * 32 + mt * 16 + quad * 4 + r;
                        float v = acc[mt][nte][r]
                                + (float)Qs[iloc * 72 + nte * 16 + ln];
                        Cout[(size_t)(b * SEQ + i0 + iloc) * HID + h * 64
                             + nte * 16 + ln] = (f16)v;
                    }
        }
    }
}

// ---------------------------------------------------------------------------
extern "C" void kernel_launch(void* const* d_in, const int* in_sizes, int n_in,
                              void* d_out, int out_size, void* d_ws, size_t ws_size,
                              hipStream_t stream) {
    const float* x  = (const float*)d_in[0];
    const float* Wq = (const float*)d_in[1];
    const float* bq = (const float*)d_in[2];
    const float* Wk = (const float*)d_in[3];
    const float* bk = (const float*)d_in[4];
    const float* Wv = (const float*)d_in[5];
    const float* bv = (const float*)d_in[6];
    const float* Wo = (const float*)d_in[7];
    const float* bo = (const float*)d_in[8];
    float* out = (float*)d_out;

    char* ws = (char*)d_ws;
    f16* xh   = (f16*)(ws);               // 8 MB  [M][1024]
    f16* WqkT = (f16*)(ws + (8 << 20));   // 2 MB  [n][k]
    f16* WvT  = (f16*)(ws + (10 << 20));  // 2 MB
    f16* WoT  = (f16*)(ws + (12 << 20));  // 2 MB
    f16* dif  = (f16*)(ws + (14 << 20));  // 8 MB  [bh][s][64]
    f16* vT   = (f16*)(ws + (22 << 20));  // 8 MB  [bh][e][s]
    f16* ctx0 = (f16*)(ws + (30 << 20));  // 8 MB  partial (x 2^-16)
    f16* ctx1 = (f16*)(ws + (38 << 20));  // 8 MB  partial

    prep<<<dim3(16, 16, 4), 256, 0, stream>>>(x, Wq, Wk, Wv, Wo,
                                              xh, WqkT, WvT, WoT);
    proj_gemm<<<dim3(MTOT / 128, 16), 256, 0, stream>>>(xh, WqkT, WvT,
                                                        bq, bk, bv, dif, vT);
    attn_f16<<<1024, 256, 0, stream>>>(dif, vT, ctx0, ctx1);
    out_gemm<<<dim3(MTOT / 128, 16), 256, 0, stream>>>(ctx0, ctx1, WoT, bo, out);
}